// Round 9
// baseline (27.783 us; speedup 1.0000x reference)
//
#include <hip/hip_runtime.h>

#define FD 128   // feature dim
#define NB 1024  // batch
#define NC 16    // classes

// ws: hi[NB*FD], hj[NB*FD], cnt[NC], lst[NC*NB]
//
// R7/R8 lesson: per-lane 16B W1 loads are the bottleneck (L1-return pipe +
// latency at low active-wave count). Fix: lane = ROW, dims in registers ->
// W1[k][d0..] is wave-uniform (one 64B line per (k,half) per block, L1-hot),
// and h is computed ONCE (no chunk redundancy). R7 also showed node overhead
// ~ 0 (bench == warm kernel), so a 2-node pipeline is cheap.

// Node 1a (bid<128): h-compute. block=(rg,dq): rows rg*64..+63, dims dq*16..+15,
//   both halves. wave = (half, dim-octet): lanes are rows, 8 acc regs.
// Node 1b (bid==128): per-class lists via LDS atomics (order nondet; the SET
//   per class is deterministic and pairs consumption is order-independent).
__global__ __launch_bounds__(256) void eg_h(
    const float* __restrict__ f, const int* __restrict__ labels,
    const float* __restrict__ W1, const float* __restrict__ b1,
    float* __restrict__ hi, float* __restrict__ hj,
    int* __restrict__ cnt, int* __restrict__ lst)
{
  const int bid = blockIdx.x;
  const int tid = threadIdx.x;

  if (bid == 128) {
    __shared__ int scnt[NC];
    if (tid < NC) scnt[tid] = 0;
    __syncthreads();
#pragma unroll
    for (int q = 0; q < 4; ++q) {
      const int j = tid + q * 256;
      const int c = labels[j];
      const int pos = atomicAdd(&scnt[c], 1);
      lst[c * NB + pos] = j;
    }
    __syncthreads();
    if (tid < NC) cnt[tid] = scnt[tid];
    return;
  }

  const int rg = bid >> 3;   // row group (16)
  const int dq = bid & 7;    // dim group of 16 (8)

  // fs4[r][slot]: f[rg*64+r][c4*4..+3] at slot=(c4+r)&31. The +r rotation
  // spreads both the b128 writes and reads uniformly 8-per-bank (optimal).
  __shared__ __align__(16) float4 fs4[64][32];
  {
    const int c4 = tid & 31;
    int r = tid >> 5;
#pragma unroll
    for (int s = 0; s < 8; ++s, r += 8) {
      fs4[r][(c4 + r) & 31] =
          *reinterpret_cast<const float4*>(f + (rg * 64 + r) * FD + c4 * 4);
    }
  }
  __syncthreads();

  const int lane = tid & 63;          // = row within group
  const int wv   = tid >> 6;
  const int half = wv >> 1;           // 0: hi (W1[:D], +b1)  1: hj (W1[D:])
  const int d0   = dq * 16 + (wv & 1) * 8;

  float acc[8];
#pragma unroll
  for (int x = 0; x < 8; ++x) acc[x] = 0.f;
  if (half == 0) {
    const float4 bA = *reinterpret_cast<const float4*>(b1 + d0);
    const float4 bB = *reinterpret_cast<const float4*>(b1 + d0 + 4);
    acc[0] = bA.x; acc[1] = bA.y; acc[2] = bA.z; acc[3] = bA.w;
    acc[4] = bB.x; acc[5] = bB.y; acc[6] = bB.z; acc[7] = bB.w;
  }

  const float* __restrict__ Wp = W1 + (half ? FD * FD : 0) + d0;
#pragma unroll 4
  for (int k4 = 0; k4 < 32; ++k4) {
    const float4 f4 = fs4[lane][(k4 + lane) & 31];   // ds_read_b128
    const float* fq = reinterpret_cast<const float*>(&f4);
#pragma unroll
    for (int kk = 0; kk < 4; ++kk) {
      const int k = k4 * 4 + kk;
      // wave-uniform address: one 64B line per (k,half), shared by both
      // dim-octet waves of this half -> 256 unique lines/block, L1-resident.
      const float4 wA = *reinterpret_cast<const float4*>(Wp + k * FD);
      const float4 wB = *reinterpret_cast<const float4*>(Wp + k * FD + 4);
      const float fv = fq[kk];
      acc[0] = fmaf(fv, wA.x, acc[0]); acc[1] = fmaf(fv, wA.y, acc[1]);
      acc[2] = fmaf(fv, wA.z, acc[2]); acc[3] = fmaf(fv, wA.w, acc[3]);
      acc[4] = fmaf(fv, wB.x, acc[4]); acc[5] = fmaf(fv, wB.y, acc[5]);
      acc[6] = fmaf(fv, wB.z, acc[6]); acc[7] = fmaf(fv, wB.w, acc[7]);
    }
  }

  float* __restrict__ dst =
      (half ? hj : hi) + (size_t)(rg * 64 + lane) * FD + d0;
  *reinterpret_cast<float4*>(dst) =
      make_float4(acc[0], acc[1], acc[2], acc[3]);
  *reinterpret_cast<float4*>(dst + 4) =
      make_float4(acc[4], acc[5], acc[6], acc[7]);
}

// Node 2: block = output row i. Zero own 4KB row, then 4 waves stride the
// class list with 2-pair ILP; lanes split dims (2 each); coalesced 512B
// hj-row loads (L2-resident); shuffle-tree reduce; sigmoid scatter.
__global__ __launch_bounds__(256) void eg_pairs(
    const float* __restrict__ hi, const float* __restrict__ hj,
    const float* __restrict__ w2, const float* __restrict__ b2,
    const int* __restrict__ labels, const int* __restrict__ cnt,
    const int* __restrict__ lst, float* __restrict__ out)
{
  const int i = blockIdx.x;
  float* __restrict__ row = out + (size_t)i * NB;

  // masked elems must be exactly 0 every call (harness never re-poisons)
  *reinterpret_cast<float4*>(row + threadIdx.x * 4) =
      make_float4(0.f, 0.f, 0.f, 0.f);
  __syncthreads();  // zeros drained (vmcnt(0) before s_barrier) before scatter

  const int c = labels[i];
  const int n = cnt[c];
  const int lane = threadIdx.x & 63;
  const int wv = threadIdx.x >> 6;
  const float h0 = hi[i * FD + lane];
  const float h1 = hi[i * FD + lane + 64];
  const float w0 = w2[lane];
  const float w1 = w2[lane + 64];
  const float bb = b2[0];
  const int* __restrict__ cls = lst + c * NB;

  for (int s = wv; s < n; s += 8) {
    const int s1 = s + 4;
    const bool has1 = s1 < n;
    const int j0 = cls[s];
    const int j1 = has1 ? cls[s1] : j0;
    float a0 = fmaxf(h0 + hj[j0 * FD + lane], 0.f) * w0 +
               fmaxf(h1 + hj[j0 * FD + lane + 64], 0.f) * w1;
    float a1 = fmaxf(h0 + hj[j1 * FD + lane], 0.f) * w0 +
               fmaxf(h1 + hj[j1 * FD + lane + 64], 0.f) * w1;
#pragma unroll
    for (int m = 32; m; m >>= 1) {
      a0 += __shfl_xor(a0, m, 64);
      a1 += __shfl_xor(a1, m, 64);
    }
    if (lane == 0) {
      if (j0 != i) row[j0] = 1.f / (1.f + __expf(-(a0 + bb)));
      if (has1 && j1 != i) row[j1] = 1.f / (1.f + __expf(-(a1 + bb)));
    }
  }
}

extern "C" void kernel_launch(void* const* d_in, const int* in_sizes, int n_in,
                              void* d_out, int out_size, void* d_ws, size_t ws_size,
                              hipStream_t stream) {
  const float* f      = (const float*)d_in[0];
  const int*   labels = (const int*)d_in[1];
  const float* W1     = (const float*)d_in[2];
  const float* b1     = (const float*)d_in[3];
  const float* w2     = (const float*)d_in[4];
  const float* b2     = (const float*)d_in[5];
  float* out = (float*)d_out;

  float* hi = (float*)d_ws;
  float* hj = hi + NB * FD;
  int*   cnt = (int*)(hj + NB * FD);
  int*   lst = cnt + NC;

  eg_h<<<129, 256, 0, stream>>>(f, labels, W1, b1, hi, hj, cnt, lst);
  eg_pairs<<<NB, 256, 0, stream>>>(hi, hj, w2, b2, labels, cnt, lst, out);
}

// Round 10
// 27.235 us; speedup vs baseline: 1.0201x; 1.0201x over previous
//
#include <hip/hip_runtime.h>

#define FD 128          // feature dim
#define NB 1024         // batch
#define NC 16           // classes
#define NCB (NC * 16)   // 256 class blocks: 16 classes x (4x4 i,j chunks)
#define MAXM 112        // max supported class size (mean 64, sd ~7.7)
#define CKCAP 28        // ceil(MAXM/4) rows per chunk
#define LDP 132         // LDS row stride (floats): 16B-aligned, bank phase +4/row

// ONE kernel (R1-R9 fit: bench ~= 17us fixed + 4-5us/extra-node + work ->
// single node mandatory). Output partitioned write-disjointly:
//   class blocks (bid < NCB): class c = bid>>4, (qi,qj) chunk pair -> scores.
//   fill blocks  (bid >= NCB): row i = bid-NCB, zeros where labels differ.
// Member list built by deterministic ballot prefix-scan (identical in every
// block of a class) -> each (i,j) owned by exactly one block.
//
// R4: read W1 once per pass (broadcast column loads), don't stream per task.
// R6/R7: need low bytes/FMA AND issue efficiency; R5's 256-thr 4rows x 8dims
//   layout is the best measured (22.96us).
// R10: R5 wasted half its h-issue on clamped rows (covers 32 rows, typical
//   chunk S=16). Split k-loop: rows {r8,r8+8} always; rows {r8+16,r8+24} in a
//   second loop guarded by r8+16<S -> for S<=16 whole waves skip it (execz).
__global__ __launch_bounds__(256) void eg_one(
    const float* __restrict__ f, const int* __restrict__ labels,
    const float* __restrict__ W1, const float* __restrict__ b1,
    const float* __restrict__ w2, const float* __restrict__ b2,
    float* __restrict__ out)
{
  const int bid = blockIdx.x;
  const int tid = threadIdx.x;

  if (bid >= NCB) {
    // ---------- fill path ----------
    const int i = bid - NCB;
    const int li = labels[i];
    float* __restrict__ row = out + (size_t)i * NB;
#pragma unroll
    for (int q = 0; q < 4; ++q) {
      const int j = tid + q * 256;
      if (labels[j] != li) row[j] = 0.f;   // masked elems must be exactly 0
    }
    return;
  }

  // ---------- class path ----------
  // lds union (barrier-separated lifetimes):
  //   phase 1: fs[2*CKCAP][LDP]  staged f rows (i-chunk then j-chunk)
  //   phase 2: his[CKCAP][LDP] | hjs[CKCAP][LDP]
  __shared__ __align__(16) float lds[2 * CKCAP * LDP];
  __shared__ int mem[MAXM];
  __shared__ int mcnt;
  float (*fs)[LDP]  = reinterpret_cast<float (*)[LDP]>(lds);
  float (*his)[LDP] = reinterpret_cast<float (*)[LDP]>(lds);
  float (*hjs)[LDP] = reinterpret_cast<float (*)[LDP]>(lds + CKCAP * LDP);

  const int c  = bid >> 4;
  const int qi = (bid >> 2) & 3;
  const int qj = bid & 3;

  // Deterministic member list (wave 0): ballot prefix over ascending j.
  if (tid < 64) {
    const int lane = tid;
    int base = 0;
    for (int w = 0; w < 16; ++w) {
      const int j = w * 64 + lane;
      const bool fl = (labels[j] == c);
      const unsigned long long msk = __ballot(fl);
      const int pos = base + __popcll(msk & ((1ull << lane) - 1ull));
      if (fl && pos < MAXM) mem[pos] = j;
      base += __popcll(msk);
    }
    if (lane == 0) mcnt = base < MAXM ? base : MAXM;
  }
  __syncthreads();

  const int m  = mcnt;
  const int ck = (m + 3) >> 2;                       // ceil(m/4) <= CKCAP
  const int i0 = qi * ck;
  const int SI = max(0, min(m, i0 + ck) - i0);
  const int j0 = qj * ck;
  const int SJ = max(0, min(m, j0 + ck) - j0);
  const int R  = SI + SJ;

  // Stage f rows of both chunks into LDS (coalesced float4).
  for (int idx = tid; idx < R * 32; idx += 256) {
    const int r  = idx >> 5;
    const int fo = (idx & 31) << 2;
    const int g  = (r < SI) ? mem[i0 + r] : mem[j0 + (r - SI)];
    *reinterpret_cast<float4*>(&fs[r][fo]) =
        *reinterpret_cast<const float4*>(f + g * FD + fo);
  }
  __syncthreads();

  // h-compute: thread = (half, r8, dg); half 0 -> hi (b1 folded, W1[:D]),
  // half 1 -> hj (W1[D:]). Loop A: rows r8, r8+8 (always). Loop B: rows
  // r8+16, r8+24, only when r8+16 < S -- waves with no such row skip via
  // execz; typical S=16 skips Loop B everywhere, halving h-issue vs R5.
  const int half  = tid >> 7;
  const int r8    = (tid >> 4) & 7;
  const int dg    = (tid & 15) << 3;
  const int S     = half ? SJ : SI;
  const int rbase = half ? SI : 0;

  float4 bA = make_float4(0.f, 0.f, 0.f, 0.f), bB = bA;
  if (!half) {
    bA = *reinterpret_cast<const float4*>(b1 + dg);
    bB = *reinterpret_cast<const float4*>(b1 + dg + 4);
  }
  const float* __restrict__ Wp = W1 + half * FD * FD + dg;

  float accA[2][8], accB[2][8];
#pragma unroll
  for (int rr = 0; rr < 2; ++rr) {
    accA[rr][0] = bA.x; accA[rr][1] = bA.y; accA[rr][2] = bA.z; accA[rr][3] = bA.w;
    accA[rr][4] = bB.x; accA[rr][5] = bB.y; accA[rr][6] = bB.z; accA[rr][7] = bB.w;
    accB[rr][0] = bA.x; accB[rr][1] = bA.y; accB[rr][2] = bA.z; accB[rr][3] = bA.w;
    accB[rr][4] = bB.x; accB[rr][5] = bB.y; accB[rr][6] = bB.z; accB[rr][7] = bB.w;
  }

  {  // Loop A: rows r8, r8+8
    const float* fr0 = fs[rbase + (r8 < S ? r8 : 0)];
    const float* fr1 = fs[rbase + (r8 + 8 < S ? r8 + 8 : 0)];
#pragma unroll 4
    for (int k = 0; k < FD; ++k) {
      const float4 wA = *reinterpret_cast<const float4*>(Wp + k * FD);
      const float4 wB = *reinterpret_cast<const float4*>(Wp + k * FD + 4);
      const float f0 = fr0[k], f1 = fr1[k];
      accA[0][0] = fmaf(f0, wA.x, accA[0][0]); accA[0][1] = fmaf(f0, wA.y, accA[0][1]);
      accA[0][2] = fmaf(f0, wA.z, accA[0][2]); accA[0][3] = fmaf(f0, wA.w, accA[0][3]);
      accA[0][4] = fmaf(f0, wB.x, accA[0][4]); accA[0][5] = fmaf(f0, wB.y, accA[0][5]);
      accA[0][6] = fmaf(f0, wB.z, accA[0][6]); accA[0][7] = fmaf(f0, wB.w, accA[0][7]);
      accA[1][0] = fmaf(f1, wA.x, accA[1][0]); accA[1][1] = fmaf(f1, wA.y, accA[1][1]);
      accA[1][2] = fmaf(f1, wA.z, accA[1][2]); accA[1][3] = fmaf(f1, wA.w, accA[1][3]);
      accA[1][4] = fmaf(f1, wB.x, accA[1][4]); accA[1][5] = fmaf(f1, wB.y, accA[1][5]);
      accA[1][6] = fmaf(f1, wB.z, accA[1][6]); accA[1][7] = fmaf(f1, wB.w, accA[1][7]);
    }
  }
  if (r8 + 16 < S) {  // Loop B: rows r8+16, r8+24 (skipped wave-wide if none)
    const float* fr0 = fs[rbase + r8 + 16];
    const float* fr1 = fs[rbase + (r8 + 24 < S ? r8 + 24 : 0)];
#pragma unroll 4
    for (int k = 0; k < FD; ++k) {
      const float4 wA = *reinterpret_cast<const float4*>(Wp + k * FD);
      const float4 wB = *reinterpret_cast<const float4*>(Wp + k * FD + 4);
      const float f0 = fr0[k], f1 = fr1[k];
      accB[0][0] = fmaf(f0, wA.x, accB[0][0]); accB[0][1] = fmaf(f0, wA.y, accB[0][1]);
      accB[0][2] = fmaf(f0, wA.z, accB[0][2]); accB[0][3] = fmaf(f0, wA.w, accB[0][3]);
      accB[0][4] = fmaf(f0, wB.x, accB[0][4]); accB[0][5] = fmaf(f0, wB.y, accB[0][5]);
      accB[0][6] = fmaf(f0, wB.z, accB[0][6]); accB[0][7] = fmaf(f0, wB.w, accB[0][7]);
      accB[1][0] = fmaf(f1, wA.x, accB[1][0]); accB[1][1] = fmaf(f1, wA.y, accB[1][1]);
      accB[1][2] = fmaf(f1, wA.z, accB[1][2]); accB[1][3] = fmaf(f1, wA.w, accB[1][3]);
      accB[1][4] = fmaf(f1, wB.x, accB[1][4]); accB[1][5] = fmaf(f1, wB.y, accB[1][5]);
      accB[1][6] = fmaf(f1, wB.z, accB[1][6]); accB[1][7] = fmaf(f1, wB.w, accB[1][7]);
    }
  }
  __syncthreads();   // all fs reads complete before lds is reused as his/hjs

#pragma unroll
  for (int rr = 0; rr < 2; ++rr) {
    const int rA = r8 + rr * 8;
    if (rA < S) {
      float* dst = (half ? hjs[rA] : his[rA]) + dg;
      *reinterpret_cast<float4*>(dst) =
          make_float4(accA[rr][0], accA[rr][1], accA[rr][2], accA[rr][3]);
      *reinterpret_cast<float4*>(dst + 4) =
          make_float4(accA[rr][4], accA[rr][5], accA[rr][6], accA[rr][7]);
    }
    const int rB = r8 + 16 + rr * 8;
    if (rB < S) {
      float* dst = (half ? hjs[rB] : his[rB]) + dg;
      *reinterpret_cast<float4*>(dst) =
          make_float4(accB[rr][0], accB[rr][1], accB[rr][2], accB[rr][3]);
      *reinterpret_cast<float4*>(dst + 4) =
          make_float4(accB[rr][4], accB[rr][5], accB[rr][6], accB[rr][7]);
    }
  }
  __syncthreads();

  // pairs: per wave an 8x8 (i,j) tile; lane owns one pair; float4 d-loop.
  // stride-132 rows -> 8 row-addresses spread across banks, conflict-free.
  const int wv = tid >> 6, lane = tid & 63;
  const int a = lane >> 3, b = lane & 7;
  const int nti = (SI + 7) >> 3, ntj = (SJ + 7) >> 3;
  const float bb = b2[0];
  for (int t = wv; t < nti * ntj; t += 4) {
    const int ti = t / ntj, tj = t - ti * ntj;
    const int ii = ti * 8 + a, jj = tj * 8 + b;
    const int ic = ii < SI ? ii : SI - 1;   // clamp: keep LDS reads in-bounds
    const int jc = jj < SJ ? jj : SJ - 1;
    float acc2 = 0.f;
#pragma unroll 8
    for (int d = 0; d < FD; d += 4) {
      const float4 hv = *reinterpret_cast<const float4*>(&his[ic][d]);
      const float4 gv = *reinterpret_cast<const float4*>(&hjs[jc][d]);
      const float4 w4 = *reinterpret_cast<const float4*>(&w2[d]);
      acc2 = fmaf(fmaxf(hv.x + gv.x, 0.f), w4.x, acc2);
      acc2 = fmaf(fmaxf(hv.y + gv.y, 0.f), w4.y, acc2);
      acc2 = fmaf(fmaxf(hv.z + gv.z, 0.f), w4.z, acc2);
      acc2 = fmaf(fmaxf(hv.w + gv.w, 0.f), w4.w, acc2);
    }
    if (ii < SI && jj < SJ) {
      const int gi = mem[i0 + ii], gj = mem[j0 + jj];
      out[(size_t)gi * NB + gj] =
          (gi == gj) ? 0.f : 1.f / (1.f + __expf(-(acc2 + bb)));
    }
  }
}

extern "C" void kernel_launch(void* const* d_in, const int* in_sizes, int n_in,
                              void* d_out, int out_size, void* d_ws, size_t ws_size,
                              hipStream_t stream) {
  const float* f      = (const float*)d_in[0];
  const int*   labels = (const int*)d_in[1];
  const float* W1     = (const float*)d_in[2];
  const float* b1     = (const float*)d_in[3];
  const float* w2     = (const float*)d_in[4];
  const float* b2     = (const float*)d_in[5];
  float* out = (float*)d_out;

  eg_one<<<NCB + NB, 256, 0, stream>>>(f, labels, W1, b1, w2, b2, out);
}

// Round 11
// 21.990 us; speedup vs baseline: 1.2634x; 1.2385x over previous
//
#include <hip/hip_runtime.h>

typedef float f2 __attribute__((ext_vector_type(2)));

#define FD 128          // feature dim
#define NB 1024         // batch
#define NC 16           // classes
#define NCB (NC * 16)   // 256 class blocks: 16 classes x (4x4 i,j chunks)
#define MAXM 112        // max supported class size (mean 64, sd ~7.7)
#define CKCAP 28        // ceil(MAXM/4) rows per chunk
#define LDP 132         // LDS row stride (floats): 16B-aligned, bank phase +4/row

// ONE kernel (R1-R10 fit: bench ~= 17us fixed + 4-5us/extra-node + work ->
// single node mandatory). Output partitioned write-disjointly:
//   class blocks (bid < NCB): class c = bid>>4, (qi,qj) chunk pair -> scores.
//   fill blocks  (bid >= NCB): row i = bid-NCB, zeros where labels differ.
// Member list built by deterministic ballot prefix-scan (identical in every
// block of a class) -> each (i,j) owned by exactly one block.
//
// R4: read W1 once per pass (broadcast column loads), don't stream per task.
// R6/R7: need low bytes/FMA AND multi-row register blocking; R5's 256-thr
//   (half, r8, dg) 4-rows x 8-dims layout is the best measured (22.96us).
// R10: guarded second k-loop for rows 16..31 REGRESSED — classes with S=17..20
//   trigger it nearly empty; clamp-and-discard (this version) is better.
// R11: pack FMAs as v_pk_fma_f32 (f2 + __builtin_elementwise_fma). In the
//   issue-bound 1-wave/SIMD regime this halves FMA instruction count
//   (76->44 cyc per k). Downside bounded: if pk is half-rate/scalarized,
//   cycles are identical to R5.
__global__ __launch_bounds__(256) void eg_one(
    const float* __restrict__ f, const int* __restrict__ labels,
    const float* __restrict__ W1, const float* __restrict__ b1,
    const float* __restrict__ w2, const float* __restrict__ b2,
    float* __restrict__ out)
{
  const int bid = blockIdx.x;
  const int tid = threadIdx.x;

  if (bid >= NCB) {
    // ---------- fill path ----------
    const int i = bid - NCB;
    const int li = labels[i];
    float* __restrict__ row = out + (size_t)i * NB;
#pragma unroll
    for (int q = 0; q < 4; ++q) {
      const int j = tid + q * 256;
      if (labels[j] != li) row[j] = 0.f;   // masked elems must be exactly 0
    }
    return;
  }

  // ---------- class path ----------
  // lds union (barrier-separated lifetimes):
  //   phase 1: fs[2*CKCAP][LDP]  staged f rows (i-chunk then j-chunk)
  //   phase 2: his[CKCAP][LDP] | hjs[CKCAP][LDP]
  __shared__ __align__(16) float lds[2 * CKCAP * LDP];
  __shared__ int mem[MAXM];
  __shared__ int mcnt;
  float (*fs)[LDP]  = reinterpret_cast<float (*)[LDP]>(lds);
  float (*his)[LDP] = reinterpret_cast<float (*)[LDP]>(lds);
  float (*hjs)[LDP] = reinterpret_cast<float (*)[LDP]>(lds + CKCAP * LDP);

  const int c  = bid >> 4;
  const int qi = (bid >> 2) & 3;
  const int qj = bid & 3;

  // Deterministic member list (wave 0): ballot prefix over ascending j.
  if (tid < 64) {
    const int lane = tid;
    int base = 0;
    for (int w = 0; w < 16; ++w) {
      const int j = w * 64 + lane;
      const bool fl = (labels[j] == c);
      const unsigned long long msk = __ballot(fl);
      const int pos = base + __popcll(msk & ((1ull << lane) - 1ull));
      if (fl && pos < MAXM) mem[pos] = j;
      base += __popcll(msk);
    }
    if (lane == 0) mcnt = base < MAXM ? base : MAXM;
  }
  __syncthreads();

  const int m  = mcnt;
  const int ck = (m + 3) >> 2;                       // ceil(m/4) <= CKCAP
  const int i0 = qi * ck;
  const int SI = max(0, min(m, i0 + ck) - i0);
  const int j0 = qj * ck;
  const int SJ = max(0, min(m, j0 + ck) - j0);
  const int R  = SI + SJ;

  // Stage f rows of both chunks into LDS (coalesced float4).
  for (int idx = tid; idx < R * 32; idx += 256) {
    const int r  = idx >> 5;
    const int fo = (idx & 31) << 2;
    const int g  = (r < SI) ? mem[i0 + r] : mem[j0 + (r - SI)];
    *reinterpret_cast<float4*>(&fs[r][fo]) =
        *reinterpret_cast<const float4*>(f + g * FD + fo);
  }
  __syncthreads();

  // h-compute: thread = (half, r8, dg) -> rows {r8,r8+8,r8+16,r8+24} x 8 dims.
  // half 0 -> hi (b1 folded, W1[:D]); half 1 -> hj (W1[D:]).
  const int half  = tid >> 7;
  const int r8    = (tid >> 4) & 7;
  const int dg    = (tid & 15) << 3;
  const int S     = half ? SJ : SI;
  const int rbase = half ? SI : 0;

  f2 acc[4][4];
  {
    f2 b01 = {0.f, 0.f}, b23 = b01, b45 = b01, b67 = b01;
    if (!half) {
      const f2* bp = reinterpret_cast<const f2*>(b1 + dg);
      b01 = bp[0]; b23 = bp[1]; b45 = bp[2]; b67 = bp[3];
    }
#pragma unroll
    for (int rr = 0; rr < 4; ++rr) {
      acc[rr][0] = b01; acc[rr][1] = b23; acc[rr][2] = b45; acc[rr][3] = b67;
    }
  }
  const float* frow[4];
#pragma unroll
  for (int rr = 0; rr < 4; ++rr) {
    const int r = r8 + rr * 8;
    frow[rr] = fs[rbase + (r < S ? r : 0)];   // clamped rows discarded at write
  }
  const float* __restrict__ Wp = W1 + half * FD * FD + dg;
#pragma unroll 4
  for (int k = 0; k < FD; ++k) {
    const f2* wp = reinterpret_cast<const f2*>(Wp + k * FD);  // 8 floats = 2x16B loads
    const f2 wv0 = wp[0], wv1 = wp[1], wv2 = wp[2], wv3 = wp[3];
#pragma unroll
    for (int rr = 0; rr < 4; ++rr) {
      const float fv = frow[rr][k];
      const f2 fvv = {fv, fv};
      acc[rr][0] = __builtin_elementwise_fma(fvv, wv0, acc[rr][0]);
      acc[rr][1] = __builtin_elementwise_fma(fvv, wv1, acc[rr][1]);
      acc[rr][2] = __builtin_elementwise_fma(fvv, wv2, acc[rr][2]);
      acc[rr][3] = __builtin_elementwise_fma(fvv, wv3, acc[rr][3]);
    }
  }
  __syncthreads();   // all fs reads complete before lds is reused as his/hjs

#pragma unroll
  for (int rr = 0; rr < 4; ++rr) {
    const int r = r8 + rr * 8;
    if (r < S) {
      float* dst = (half ? hjs[r] : his[r]) + dg;
      f2* d2 = reinterpret_cast<f2*>(dst);
      d2[0] = acc[rr][0]; d2[1] = acc[rr][1];
      d2[2] = acc[rr][2]; d2[3] = acc[rr][3];
    }
  }
  __syncthreads();

  // pairs: per wave an 8x8 (i,j) tile; lane owns one pair; float4 d-loop,
  // packed relu/fma. stride-132 rows spread across banks, conflict-free.
  const int wv = tid >> 6, lane = tid & 63;
  const int a = lane >> 3, b = lane & 7;
  const int nti = (SI + 7) >> 3, ntj = (SJ + 7) >> 3;
  const float bb = b2[0];
  const f2 z2 = {0.f, 0.f};
  for (int t = wv; t < nti * ntj; t += 4) {
    const int ti = t / ntj, tj = t - ti * ntj;
    const int ii = ti * 8 + a, jj = tj * 8 + b;
    const int ic = ii < SI ? ii : SI - 1;   // clamp: keep LDS reads in-bounds
    const int jc = jj < SJ ? jj : SJ - 1;
    f2 accp = z2;
#pragma unroll 8
    for (int d = 0; d < FD; d += 4) {
      const float4 hv = *reinterpret_cast<const float4*>(&his[ic][d]);
      const float4 gv = *reinterpret_cast<const float4*>(&hjs[jc][d]);
      const float4 w4 = *reinterpret_cast<const float4*>(&w2[d]);
      const f2 h01 = {hv.x, hv.y}, h23 = {hv.z, hv.w};
      const f2 g01 = {gv.x, gv.y}, g23 = {gv.z, gv.w};
      const f2 u01 = {w4.x, w4.y}, u23 = {w4.z, w4.w};
      accp = __builtin_elementwise_fma(
          __builtin_elementwise_max(h01 + g01, z2), u01, accp);
      accp = __builtin_elementwise_fma(
          __builtin_elementwise_max(h23 + g23, z2), u23, accp);
    }
    if (ii < SI && jj < SJ) {
      const int gi = mem[i0 + ii], gj = mem[j0 + jj];
      const float acc2 = accp.x + accp.y;
      out[(size_t)gi * NB + gj] =
          (gi == gj) ? 0.f : 1.f / (1.f + __expf(-(acc2 + bb)));
    }
  }
}

extern "C" void kernel_launch(void* const* d_in, const int* in_sizes, int n_in,
                              void* d_out, int out_size, void* d_ws, size_t ws_size,
                              hipStream_t stream) {
  const float* f      = (const float*)d_in[0];
  const int*   labels = (const int*)d_in[1];
  const float* W1     = (const float*)d_in[2];
  const float* b1     = (const float*)d_in[3];
  const float* w2     = (const float*)d_in[4];
  const float* b2     = (const float*)d_in[5];
  float* out = (float*)d_out;

  eg_one<<<NCB + NB, 256, 0, stream>>>(f, labels, W1, b1, w2, b2, out);
}